// Round 1
// baseline (2187.402 us; speedup 1.0000x reference)
//
#include <hip/hip_runtime.h>

#define IN_CH 16
#define HID 128
#define HEADS 4
#define CPH 32
#define NEG 0.2f
#define LN_EPS 1e-5f

// ---------------------------------------------------------------------------
// Kernel 1: h1 = x @ W1  (N x 16 @ 16 x 128), fused per-head attention logits
// block = 128 threads = one node; col c = threadIdx.x
// ---------------------------------------------------------------------------
__global__ __launch_bounds__(128) void k_gemm1(
    const float* __restrict__ x, const float* __restrict__ W1,
    const float* __restrict__ a_src, const float* __restrict__ a_dst,
    float* __restrict__ h1, float* __restrict__ asrc, float* __restrict__ adst,
    int N) {
  int n = blockIdx.x;
  int c = threadIdx.x;
  __shared__ float xs[IN_CH];
  if (c < IN_CH) xs[c] = x[n * IN_CH + c];
  __syncthreads();
  float acc = 0.f;
#pragma unroll
  for (int k = 0; k < IN_CH; ++k) acc += xs[k] * W1[k * HID + c];
  h1[(long long)n * HID + c] = acc;
  // per-head (32-lane) reductions for attention logits
  float av = acc * a_src[c];
  float dv = acc * a_dst[c];
#pragma unroll
  for (int o = 16; o > 0; o >>= 1) {
    av += __shfl_down(av, o, 32);
    dv += __shfl_down(dv, o, 32);
  }
  if ((c & 31) == 0) {
    asrc[n * HEADS + (c >> 5)] = av;
    adst[n * HEADS + (c >> 5)] = dv;
  }
}

// ---------------------------------------------------------------------------
// Edge pass: softmax denominators, layer 1 (4 heads). 1 thread / edge.
// ---------------------------------------------------------------------------
__global__ __launch_bounds__(256) void k_denom1(
    const int* __restrict__ ei, int E, int Etot,
    const float* __restrict__ asrc, const float* __restrict__ adst,
    float* __restrict__ denom) {
  int e = blockIdx.x * 256 + threadIdx.x;
  if (e >= Etot) return;
  int s, d;
  if (e < E) { s = ei[e]; d = ei[E + e]; } else { s = d = e - E; }
#pragma unroll
  for (int h = 0; h < HEADS; ++h) {
    float v = asrc[s * HEADS + h] + adst[d * HEADS + h];
    v = v < 0.f ? NEG * v : v;
    atomicAdd(&denom[d * HEADS + h], __expf(v));
  }
}

// ---------------------------------------------------------------------------
// Edge pass: message aggregation, layer 1. 128 threads / edge.
// ---------------------------------------------------------------------------
__global__ __launch_bounds__(256) void k_msg1(
    const int* __restrict__ ei, int E, int Etot,
    const float* __restrict__ asrc, const float* __restrict__ adst,
    const float* __restrict__ denom, const float* __restrict__ h1,
    float* __restrict__ out) {
  int t = blockIdx.x * 256 + threadIdx.x;
  int total = Etot * HID;  // 217.6M < 2^31
  if (t >= total) return;
  int e = t >> 7;
  int col = t & 127;
  int h = col >> 5;
  int s, d;
  if (e < E) { s = ei[e]; d = ei[E + e]; } else { s = d = e - E; }
  float v = asrc[s * HEADS + h] + adst[d * HEADS + h];
  v = v < 0.f ? NEG * v : v;
  float alpha = __expf(v) / denom[d * HEADS + h];
  atomicAdd(&out[(long long)d * HID + col], h1[(long long)s * HID + col] * alpha);
}

// ---------------------------------------------------------------------------
// bias + ELU + LayerNorm per node. block = 128 = one node.
// ---------------------------------------------------------------------------
__global__ __launch_bounds__(128) void k_eluln(
    const float* __restrict__ in, const float* __restrict__ bias,
    const float* __restrict__ g, const float* __restrict__ beta,
    float* __restrict__ out) {
  int n = blockIdx.x;
  int c = threadIdx.x;
  float v = in[(long long)n * HID + c] + bias[c];
  v = v > 0.f ? v : (__expf(v) - 1.f);
  float s1 = v, s2 = v * v;
#pragma unroll
  for (int o = 32; o > 0; o >>= 1) {
    s1 += __shfl_down(s1, o, 64);
    s2 += __shfl_down(s2, o, 64);
  }
  __shared__ float r1[2], r2[2];
  int w = c >> 6;
  if ((c & 63) == 0) { r1[w] = s1; r2[w] = s2; }
  __syncthreads();
  float sum = r1[0] + r1[1];
  float sumsq = r2[0] + r2[1];
  float mu = sum * (1.f / HID);
  float var = sumsq * (1.f / HID) - mu * mu;
  float inv = rsqrtf(var + LN_EPS);
  out[(long long)n * HID + c] = (v - mu) * inv * g[c] + beta[c];
}

// ---------------------------------------------------------------------------
// Kernel: h2 = x2 @ W2 (N x 128 @ 128 x 128). block=256, 8 nodes/block.
// slot = tid>>7 handles 4 nodes with 4 accumulators (amortize W2 column load).
// ---------------------------------------------------------------------------
__global__ __launch_bounds__(256) void k_gemm2(
    const float* __restrict__ x2, const float* __restrict__ W2,
    float* __restrict__ h2, int N) {
  const int NB = 8;
  int nb = blockIdx.x * NB;
  int col = threadIdx.x & 127;
  int slot = threadIdx.x >> 7;  // 0..1
  __shared__ float xs[NB][HID];
  for (int i = threadIdx.x; i < NB * HID; i += 256) {
    int node = nb + (i >> 7);
    xs[i >> 7][i & 127] = (node < N) ? x2[(long long)node * HID + (i & 127)] : 0.f;
  }
  __syncthreads();
  float a0 = 0.f, a1 = 0.f, a2 = 0.f, a3 = 0.f;
  const float* xr = &xs[slot * 4][0];
#pragma unroll 8
  for (int k = 0; k < HID; ++k) {
    float w = W2[k * HID + col];
    a0 += xr[0 * HID + k] * w;
    a1 += xr[1 * HID + k] * w;
    a2 += xr[2 * HID + k] * w;
    a3 += xr[3 * HID + k] * w;
  }
  int base = nb + slot * 4;
  if (base + 0 < N) h2[(long long)(base + 0) * HID + col] = a0;
  if (base + 1 < N) h2[(long long)(base + 1) * HID + col] = a1;
  if (base + 2 < N) h2[(long long)(base + 2) * HID + col] = a2;
  if (base + 3 < N) h2[(long long)(base + 3) * HID + col] = a3;
}

// ---------------------------------------------------------------------------
// alpha logits layer 2 (heads=1): one wave (64 lanes) per node, 128-len dot.
// ---------------------------------------------------------------------------
__global__ __launch_bounds__(256) void k_alpha2(
    const float* __restrict__ h2, const float* __restrict__ a_src,
    const float* __restrict__ a_dst, float* __restrict__ asrc,
    float* __restrict__ adst, int N) {
  int n = blockIdx.x * 4 + (threadIdx.x >> 6);
  int l = threadIdx.x & 63;
  if (n >= N) return;
  float v0 = h2[(long long)n * HID + l];
  float v1 = h2[(long long)n * HID + 64 + l];
  float av = v0 * a_src[l] + v1 * a_src[64 + l];
  float dv = v0 * a_dst[l] + v1 * a_dst[64 + l];
#pragma unroll
  for (int o = 32; o > 0; o >>= 1) {
    av += __shfl_down(av, o, 64);
    dv += __shfl_down(dv, o, 64);
  }
  if (l == 0) { asrc[n] = av; adst[n] = dv; }
}

// ---------------------------------------------------------------------------
// Edge pass: softmax denominators, layer 2 (1 head). 1 thread / edge.
// ---------------------------------------------------------------------------
__global__ __launch_bounds__(256) void k_denom2(
    const int* __restrict__ ei, int E, int Etot,
    const float* __restrict__ asrc, const float* __restrict__ adst,
    float* __restrict__ denom) {
  int e = blockIdx.x * 256 + threadIdx.x;
  if (e >= Etot) return;
  int s, d;
  if (e < E) { s = ei[e]; d = ei[E + e]; } else { s = d = e - E; }
  float v = asrc[s] + adst[d];
  v = v < 0.f ? NEG * v : v;
  atomicAdd(&denom[d], __expf(v));
}

// ---------------------------------------------------------------------------
// Edge pass: message aggregation, layer 2. 128 threads / edge.
// ---------------------------------------------------------------------------
__global__ __launch_bounds__(256) void k_msg2(
    const int* __restrict__ ei, int E, int Etot,
    const float* __restrict__ asrc, const float* __restrict__ adst,
    const float* __restrict__ denom, const float* __restrict__ h2,
    float* __restrict__ out) {
  int t = blockIdx.x * 256 + threadIdx.x;
  int total = Etot * HID;
  if (t >= total) return;
  int e = t >> 7;
  int col = t & 127;
  int s, d;
  if (e < E) { s = ei[e]; d = ei[E + e]; } else { s = d = e - E; }
  float v = asrc[s] + adst[d];
  v = v < 0.f ? NEG * v : v;
  float alpha = __expf(v) / denom[d];
  atomicAdd(&out[(long long)d * HID + col], h2[(long long)s * HID + col] * alpha);
}

extern "C" void kernel_launch(void* const* d_in, const int* in_sizes, int n_in,
                              void* d_out, int out_size, void* d_ws, size_t ws_size,
                              hipStream_t stream) {
  const float* x      = (const float*)d_in[0];
  const int*   ei     = (const int*)d_in[1];
  const float* W1     = (const float*)d_in[2];
  const float* a_src1 = (const float*)d_in[3];
  const float* a_dst1 = (const float*)d_in[4];
  const float* b1     = (const float*)d_in[5];
  const float* g1     = (const float*)d_in[6];
  const float* beta1  = (const float*)d_in[7];
  const float* W2     = (const float*)d_in[8];
  const float* a_src2 = (const float*)d_in[9];
  const float* a_dst2 = (const float*)d_in[10];
  const float* b2     = (const float*)d_in[11];
  const float* g2     = (const float*)d_in[12];
  const float* beta2  = (const float*)d_in[13];
  float* out = (float*)d_out;

  const int N = in_sizes[0] / IN_CH;
  const int E = in_sizes[1] / 2;
  const int Etot = E + N;

  // workspace layout (floats)
  float* ws = (float*)d_ws;
  float* bufA   = ws;                      // h1 -> x2 -> out2   [N*128]
  float* bufB   = bufA + (long long)N * HID;  // out1 -> h2      [N*128]
  float* asrc1  = bufB + (long long)N * HID;  // [N*4]
  float* adst1  = asrc1 + (long long)N * HEADS;
  float* denom1 = adst1 + (long long)N * HEADS;  // [N*4]
  float* asrc2  = denom1 + (long long)N * HEADS; // [N]
  float* adst2  = asrc2 + N;
  float* denom2 = adst2 + N;               // [N]

  // ---- Layer 1 ----
  hipMemsetAsync(denom1, 0, (size_t)N * HEADS * sizeof(float), stream);
  hipMemsetAsync(bufB, 0, (size_t)N * HID * sizeof(float), stream);

  k_gemm1<<<N, 128, 0, stream>>>(x, W1, a_src1, a_dst1, bufA, asrc1, adst1, N);
  k_denom1<<<(Etot + 255) / 256, 256, 0, stream>>>(ei, E, Etot, asrc1, adst1, denom1);
  {
    long long total = (long long)Etot * HID;
    int blocks = (int)((total + 255) / 256);
    k_msg1<<<blocks, 256, 0, stream>>>(ei, E, Etot, asrc1, adst1, denom1, bufA, bufB);
  }
  k_eluln<<<N, 128, 0, stream>>>(bufB, b1, g1, beta1, bufA);  // x2 into bufA

  // ---- Layer 2 ----
  k_gemm2<<<(N + 7) / 8, 256, 0, stream>>>(bufA, W2, bufB, N);  // h2 into bufB
  k_alpha2<<<(N + 3) / 4, 256, 0, stream>>>(bufB, a_src2, a_dst2, asrc2, adst2, N);

  hipMemsetAsync(denom2, 0, (size_t)N * sizeof(float), stream);
  hipMemsetAsync(bufA, 0, (size_t)N * HID * sizeof(float), stream);  // out2

  k_denom2<<<(Etot + 255) / 256, 256, 0, stream>>>(ei, E, Etot, asrc2, adst2, denom2);
  {
    long long total = (long long)Etot * HID;
    int blocks = (int)((total + 255) / 256);
    k_msg2<<<blocks, 256, 0, stream>>>(ei, E, Etot, asrc2, adst2, denom2, bufB, bufA);
  }
  k_eluln<<<N, 128, 0, stream>>>(bufA, b2, g2, beta2, out);
}

// Round 2
// 832.481 us; speedup vs baseline: 2.6276x; 2.6276x over previous
//
#include <hip/hip_runtime.h>

#define IN_CH 16
#define HID 128
#define HEADS 4
#define NEG 0.2f
#define LN_EPS 1e-5f

// ---------------------------------------------------------------------------
// h1 = x @ W1 (N x 16 @ 16 x 128) fused with per-head attention logits.
// block = 128 = one node.
// ---------------------------------------------------------------------------
__global__ __launch_bounds__(128) void k_gemm1(
    const float* __restrict__ x, const float* __restrict__ W1,
    const float* __restrict__ a_src, const float* __restrict__ a_dst,
    float* __restrict__ h1, float* __restrict__ asrc, float* __restrict__ adst,
    int N) {
  int n = blockIdx.x;
  int c = threadIdx.x;
  __shared__ float xs[IN_CH];
  if (c < IN_CH) xs[c] = x[n * IN_CH + c];
  __syncthreads();
  float acc = 0.f;
#pragma unroll
  for (int k = 0; k < IN_CH; ++k) acc += xs[k] * W1[k * HID + c];
  h1[(long long)n * HID + c] = acc;
  float av = acc * a_src[c];
  float dv = acc * a_dst[c];
#pragma unroll
  for (int o = 16; o > 0; o >>= 1) {
    av += __shfl_down(av, o, 32);
    dv += __shfl_down(dv, o, 32);
  }
  if ((c & 31) == 0) {
    asrc[n * HEADS + (c >> 5)] = av;
    adst[n * HEADS + (c >> 5)] = dv;
  }
}

// ---------------------------------------------------------------------------
// CSR build: degree count (int atomics)
// ---------------------------------------------------------------------------
__global__ __launch_bounds__(256) void k_deg(
    const int* __restrict__ ei, int E, int Etot, int* __restrict__ deg) {
  int e = blockIdx.x * 256 + threadIdx.x;
  if (e >= Etot) return;
  int d = (e < E) ? ei[E + e] : (e - E);
  atomicAdd(&deg[d], 1);
}

// ---------------------------------------------------------------------------
// Scan pass 1: per-block (256-elem) exclusive scan, block totals to aux.
// ---------------------------------------------------------------------------
__global__ __launch_bounds__(256) void k_scan1(
    const int* __restrict__ deg, int* __restrict__ part, int* __restrict__ aux,
    int N) {
  int i = blockIdx.x * 256 + threadIdx.x;
  int v = (i < N) ? deg[i] : 0;
  int lane = threadIdx.x & 63, w = threadIdx.x >> 6;
  int inc = v;
#pragma unroll
  for (int o = 1; o < 64; o <<= 1) {
    int t = __shfl_up(inc, o, 64);
    if (lane >= o) inc += t;
  }
  __shared__ int wsum[4];
  if (lane == 63) wsum[w] = inc;
  __syncthreads();
  int woff = 0;
#pragma unroll
  for (int k = 0; k < 4; ++k)
    if (k < w) woff += wsum[k];
  if (i < N) part[i] = woff + inc - v;  // exclusive within block
  if (threadIdx.x == 255) aux[blockIdx.x] = woff + inc;  // block total
}

// ---------------------------------------------------------------------------
// Scan pass 2: single block exclusive-scans the block totals (nb <= 512).
// ---------------------------------------------------------------------------
__global__ __launch_bounds__(512) void k_scan2(int* __restrict__ aux, int nb) {
  int i = threadIdx.x;
  int v = (i < nb) ? aux[i] : 0;
  int lane = i & 63, w = i >> 6;
  int inc = v;
#pragma unroll
  for (int o = 1; o < 64; o <<= 1) {
    int t = __shfl_up(inc, o, 64);
    if (lane >= o) inc += t;
  }
  __shared__ int wsum[8];
  if (lane == 63) wsum[w] = inc;
  __syncthreads();
  int woff = 0;
#pragma unroll
  for (int k = 0; k < 8; ++k)
    if (k < w) woff += wsum[k];
  if (i < nb) aux[i] = woff + inc - v;
}

// ---------------------------------------------------------------------------
// Scan pass 3: combine -> rowstart, cursor. rowstart[N] = Etot.
// ---------------------------------------------------------------------------
__global__ __launch_bounds__(256) void k_scan3(
    const int* __restrict__ part, const int* __restrict__ aux,
    int* __restrict__ rowstart, int* __restrict__ cursor, int N, int Etot) {
  int i = blockIdx.x * 256 + threadIdx.x;
  if (i < N) {
    int r = part[i] + aux[blockIdx.x];
    rowstart[i] = r;
    cursor[i] = r;
  }
  if (i == 0) rowstart[N] = Etot;
}

// ---------------------------------------------------------------------------
// CSR build: scatter src indices grouped by dst (order within dst arbitrary).
// ---------------------------------------------------------------------------
__global__ __launch_bounds__(256) void k_scatter(
    const int* __restrict__ ei, int E, int Etot, int* __restrict__ cursor,
    int* __restrict__ csr_src) {
  int e = blockIdx.x * 256 + threadIdx.x;
  if (e >= Etot) return;
  int s, d;
  if (e < E) { s = ei[e]; d = ei[E + e]; } else { s = d = e - E; }
  int pos = atomicAdd(&cursor[d], 1);
  csr_src[pos] = s;
}

// ---------------------------------------------------------------------------
// Fused GAT aggregation + bias + ELU + LayerNorm, layer 1 (4 heads).
// block = 128 = one dst node; c = channel; head = c>>5.
// out[d] = (sum_e w_e * h[src_e]) / sum_e w_e   (softmax max cancels)
// ---------------------------------------------------------------------------
__global__ __launch_bounds__(128) void k_agg1(
    const int* __restrict__ rowstart, const int* __restrict__ csr_src,
    const float* __restrict__ asrc, const float* __restrict__ adst,
    const float* __restrict__ h, const float* __restrict__ bias,
    const float* __restrict__ g, const float* __restrict__ beta,
    float* __restrict__ out) {
  int d = blockIdx.x;
  int c = threadIdx.x;
  int hd = c >> 5;
  float ad = adst[d * HEADS + hd];
  int beg = rowstart[d], end = rowstart[d + 1];
  float acc = 0.f, wsum = 0.f;
  for (int i = beg; i < end; ++i) {
    int s = csr_src[i];
    float v = asrc[s * HEADS + hd] + ad;
    v = v < 0.f ? NEG * v : v;
    float w = __expf(v);
    wsum += w;
    acc += w * h[(long long)s * HID + c];
  }
  float val = acc / wsum + bias[c];
  val = val > 0.f ? val : (__expf(val) - 1.f);
  // LayerNorm over 128 channels (2 waves)
  float s1 = val, s2 = val * val;
#pragma unroll
  for (int o = 32; o > 0; o >>= 1) {
    s1 += __shfl_down(s1, o, 64);
    s2 += __shfl_down(s2, o, 64);
  }
  __shared__ float r1[2], r2[2];
  int w64 = c >> 6;
  if ((c & 63) == 0) { r1[w64] = s1; r2[w64] = s2; }
  __syncthreads();
  float sum = r1[0] + r1[1];
  float sumsq = r2[0] + r2[1];
  float mu = sum * (1.f / HID);
  float var = sumsq * (1.f / HID) - mu * mu;
  float inv = rsqrtf(var + LN_EPS);
  out[(long long)d * HID + c] = (val - mu) * inv * g[c] + beta[c];
}

// ---------------------------------------------------------------------------
// Fused GAT aggregation + bias + ELU + LayerNorm, layer 2 (1 head).
// ---------------------------------------------------------------------------
__global__ __launch_bounds__(128) void k_agg2(
    const int* __restrict__ rowstart, const int* __restrict__ csr_src,
    const float* __restrict__ asrc, const float* __restrict__ adst,
    const float* __restrict__ h, const float* __restrict__ bias,
    const float* __restrict__ g, const float* __restrict__ beta,
    float* __restrict__ out) {
  int d = blockIdx.x;
  int c = threadIdx.x;
  float ad = adst[d];
  int beg = rowstart[d], end = rowstart[d + 1];
  float acc = 0.f, wsum = 0.f;
  for (int i = beg; i < end; ++i) {
    int s = csr_src[i];
    float v = asrc[s] + ad;
    v = v < 0.f ? NEG * v : v;
    float w = __expf(v);
    wsum += w;
    acc += w * h[(long long)s * HID + c];
  }
  float val = acc / wsum + bias[c];
  val = val > 0.f ? val : (__expf(val) - 1.f);
  float s1 = val, s2 = val * val;
#pragma unroll
  for (int o = 32; o > 0; o >>= 1) {
    s1 += __shfl_down(s1, o, 64);
    s2 += __shfl_down(s2, o, 64);
  }
  __shared__ float r1[2], r2[2];
  int w64 = c >> 6;
  if ((c & 63) == 0) { r1[w64] = s1; r2[w64] = s2; }
  __syncthreads();
  float sum = r1[0] + r1[1];
  float sumsq = r2[0] + r2[1];
  float mu = sum * (1.f / HID);
  float var = sumsq * (1.f / HID) - mu * mu;
  float inv = rsqrtf(var + LN_EPS);
  out[(long long)d * HID + c] = (val - mu) * inv * g[c] + beta[c];
}

// ---------------------------------------------------------------------------
// h2 = x2 @ W2 (N x 128 @ 128 x 128). block=256, 8 nodes/block.
// ---------------------------------------------------------------------------
__global__ __launch_bounds__(256) void k_gemm2(
    const float* __restrict__ x2, const float* __restrict__ W2,
    float* __restrict__ h2, int N) {
  const int NB = 8;
  int nb = blockIdx.x * NB;
  int col = threadIdx.x & 127;
  int slot = threadIdx.x >> 7;
  __shared__ float xs[NB][HID];
  for (int i = threadIdx.x; i < NB * HID; i += 256) {
    int node = nb + (i >> 7);
    xs[i >> 7][i & 127] = (node < N) ? x2[(long long)node * HID + (i & 127)] : 0.f;
  }
  __syncthreads();
  float a0 = 0.f, a1 = 0.f, a2 = 0.f, a3 = 0.f;
  const float* xr = &xs[slot * 4][0];
#pragma unroll 8
  for (int k = 0; k < HID; ++k) {
    float w = W2[k * HID + col];
    a0 += xr[0 * HID + k] * w;
    a1 += xr[1 * HID + k] * w;
    a2 += xr[2 * HID + k] * w;
    a3 += xr[3 * HID + k] * w;
  }
  int base = nb + slot * 4;
  if (base + 0 < N) h2[(long long)(base + 0) * HID + col] = a0;
  if (base + 1 < N) h2[(long long)(base + 1) * HID + col] = a1;
  if (base + 2 < N) h2[(long long)(base + 2) * HID + col] = a2;
  if (base + 3 < N) h2[(long long)(base + 3) * HID + col] = a3;
}

// ---------------------------------------------------------------------------
// alpha logits layer 2 (heads=1): one wave per node.
// ---------------------------------------------------------------------------
__global__ __launch_bounds__(256) void k_alpha2(
    const float* __restrict__ h2, const float* __restrict__ a_src,
    const float* __restrict__ a_dst, float* __restrict__ asrc,
    float* __restrict__ adst, int N) {
  int n = blockIdx.x * 4 + (threadIdx.x >> 6);
  int l = threadIdx.x & 63;
  if (n >= N) return;
  float v0 = h2[(long long)n * HID + l];
  float v1 = h2[(long long)n * HID + 64 + l];
  float av = v0 * a_src[l] + v1 * a_src[64 + l];
  float dv = v0 * a_dst[l] + v1 * a_dst[64 + l];
#pragma unroll
  for (int o = 32; o > 0; o >>= 1) {
    av += __shfl_down(av, o, 64);
    dv += __shfl_down(dv, o, 64);
  }
  if (l == 0) { asrc[n] = av; adst[n] = dv; }
}

extern "C" void kernel_launch(void* const* d_in, const int* in_sizes, int n_in,
                              void* d_out, int out_size, void* d_ws, size_t ws_size,
                              hipStream_t stream) {
  const float* x      = (const float*)d_in[0];
  const int*   ei     = (const int*)d_in[1];
  const float* W1     = (const float*)d_in[2];
  const float* a_src1 = (const float*)d_in[3];
  const float* a_dst1 = (const float*)d_in[4];
  const float* b1     = (const float*)d_in[5];
  const float* g1     = (const float*)d_in[6];
  const float* beta1  = (const float*)d_in[7];
  const float* W2     = (const float*)d_in[8];
  const float* a_src2 = (const float*)d_in[9];
  const float* a_dst2 = (const float*)d_in[10];
  const float* b2     = (const float*)d_in[11];
  const float* g2     = (const float*)d_in[12];
  const float* beta2  = (const float*)d_in[13];
  float* out = (float*)d_out;

  const int N = in_sizes[0] / IN_CH;
  const int E = in_sizes[1] / 2;
  const int Etot = E + N;
  const int nblk = (N + 255) / 256;

  // workspace layout
  float* ws = (float*)d_ws;
  float* bufA  = ws;                           // h1 -> h2        [N*128]
  float* bufB  = bufA + (long long)N * HID;    // x2              [N*128]
  float* asrc1 = bufB + (long long)N * HID;    // [N*4]
  float* adst1 = asrc1 + (long long)N * HEADS;
  float* asrc2 = adst1 + (long long)N * HEADS; // [N]
  float* adst2 = asrc2 + N;                    // [N]
  int* ip = (int*)(adst2 + N);
  int* deg      = ip;                 // [N]
  int* part     = deg + N;            // [N]
  int* rowstart = part + N;           // [N+1]
  int* cursor   = rowstart + N + 1;   // [N]
  int* aux      = cursor + N;         // [nblk]
  int* csr_src  = aux + 1024;         // [Etot]

  // ---- CSR build (once; both layers share the graph) ----
  hipMemsetAsync(deg, 0, (size_t)N * sizeof(int), stream);
  k_deg<<<(Etot + 255) / 256, 256, 0, stream>>>(ei, E, Etot, deg);
  k_scan1<<<nblk, 256, 0, stream>>>(deg, part, aux, N);
  k_scan2<<<1, 512, 0, stream>>>(aux, nblk);
  k_scan3<<<nblk, 256, 0, stream>>>(part, aux, rowstart, cursor, N, Etot);
  k_scatter<<<(Etot + 255) / 256, 256, 0, stream>>>(ei, E, Etot, cursor, csr_src);

  // ---- Layer 1 ----
  k_gemm1<<<N, 128, 0, stream>>>(x, W1, a_src1, a_dst1, bufA, asrc1, adst1, N);
  k_agg1<<<N, 128, 0, stream>>>(rowstart, csr_src, asrc1, adst1, bufA,
                                b1, g1, beta1, bufB);

  // ---- Layer 2 ----
  k_gemm2<<<(N + 7) / 8, 256, 0, stream>>>(bufB, W2, bufA, N);
  k_alpha2<<<(N + 3) / 4, 256, 0, stream>>>(bufA, a_src2, a_dst2, asrc2, adst2, N);
  k_agg2<<<N, 128, 0, stream>>>(rowstart, csr_src, asrc2, adst2, bufA,
                                b2, g2, beta2, out);
}

// Round 3
// 576.209 us; speedup vs baseline: 3.7962x; 1.4448x over previous
//
#include <hip/hip_runtime.h>

#define IN_CH 16
#define HID 128
#define HEADS 4
#define NEG 0.2f
#define LN_EPS 1e-5f

__device__ __forceinline__ float bf2f(unsigned short u) {
  return __uint_as_float(((unsigned)u) << 16);
}
__device__ __forceinline__ unsigned short f2bf(float f) {
  unsigned u = __float_as_uint(f);
  unsigned r = (u + 0x7fffu + ((u >> 16) & 1u)) >> 16;  // RNE
  return (unsigned short)r;
}

// ---------------------------------------------------------------------------
// h1 = x @ W1 (N x 16 @ 16 x 128) -> bf16, fused per-head attention logits.
// block = 128 = one node.
// ---------------------------------------------------------------------------
__global__ __launch_bounds__(128) void k_gemm1(
    const float* __restrict__ x, const float* __restrict__ W1,
    const float* __restrict__ a_src, const float* __restrict__ a_dst,
    unsigned short* __restrict__ hb, float* __restrict__ asrc,
    float* __restrict__ adst, int N) {
  int n = blockIdx.x;
  int c = threadIdx.x;
  __shared__ float xs[IN_CH];
  if (c < IN_CH) xs[c] = x[n * IN_CH + c];
  __syncthreads();
  float acc = 0.f;
#pragma unroll
  for (int k = 0; k < IN_CH; ++k) acc += xs[k] * W1[k * HID + c];
  hb[(size_t)n * HID + c] = f2bf(acc);
  float av = acc * a_src[c];
  float dv = acc * a_dst[c];
#pragma unroll
  for (int o = 16; o > 0; o >>= 1) {
    av += __shfl_down(av, o, 32);
    dv += __shfl_down(dv, o, 32);
  }
  if ((c & 31) == 0) {
    asrc[n * HEADS + (c >> 5)] = av;
    adst[n * HEADS + (c >> 5)] = dv;
  }
}

// ---------------------------------------------------------------------------
// CSR build
// ---------------------------------------------------------------------------
__global__ __launch_bounds__(256) void k_deg(
    const int* __restrict__ ei, int E, int Etot, int* __restrict__ deg) {
  int e = blockIdx.x * 256 + threadIdx.x;
  if (e >= Etot) return;
  int d = (e < E) ? ei[E + e] : (e - E);
  atomicAdd(&deg[d], 1);
}

__global__ __launch_bounds__(256) void k_scan1(
    const int* __restrict__ deg, int* __restrict__ part, int* __restrict__ aux,
    int N) {
  int i = blockIdx.x * 256 + threadIdx.x;
  int v = (i < N) ? deg[i] : 0;
  int lane = threadIdx.x & 63, w = threadIdx.x >> 6;
  int inc = v;
#pragma unroll
  for (int o = 1; o < 64; o <<= 1) {
    int t = __shfl_up(inc, o, 64);
    if (lane >= o) inc += t;
  }
  __shared__ int wsum[4];
  if (lane == 63) wsum[w] = inc;
  __syncthreads();
  int woff = 0;
#pragma unroll
  for (int k = 0; k < 4; ++k)
    if (k < w) woff += wsum[k];
  if (i < N) part[i] = woff + inc - v;
  if (threadIdx.x == 255) aux[blockIdx.x] = woff + inc;
}

__global__ __launch_bounds__(512) void k_scan2(int* __restrict__ aux, int nb) {
  int i = threadIdx.x;
  int v = (i < nb) ? aux[i] : 0;
  int lane = i & 63, w = i >> 6;
  int inc = v;
#pragma unroll
  for (int o = 1; o < 64; o <<= 1) {
    int t = __shfl_up(inc, o, 64);
    if (lane >= o) inc += t;
  }
  __shared__ int wsum[8];
  if (lane == 63) wsum[w] = inc;
  __syncthreads();
  int woff = 0;
#pragma unroll
  for (int k = 0; k < 8; ++k)
    if (k < w) woff += wsum[k];
  if (i < nb) aux[i] = woff + inc - v;
}

__global__ __launch_bounds__(256) void k_scan3(
    const int* __restrict__ part, const int* __restrict__ aux,
    int* __restrict__ rowstart, int* __restrict__ cursor, int N, int Etot) {
  int i = blockIdx.x * 256 + threadIdx.x;
  if (i < N) {
    int r = part[i] + aux[blockIdx.x];
    rowstart[i] = r;
    cursor[i] = r;
  }
  if (i == 0) rowstart[N] = Etot;
}

__global__ __launch_bounds__(256) void k_scatter(
    const int* __restrict__ ei, int E, int Etot, int* __restrict__ cursor,
    int* __restrict__ csr_src) {
  int e = blockIdx.x * 256 + threadIdx.x;
  if (e >= Etot) return;
  int s, d;
  if (e < E) { s = ei[e]; d = ei[E + e]; } else { s = d = e - E; }
  int pos = atomicAdd(&cursor[d], 1);
  csr_src[pos] = s;
}

// ---------------------------------------------------------------------------
// Fused GAT agg + bias + ELU + LN, layer 1 (4 heads).
// 32 threads per dst node (lane holds 4 contiguous channels, ushort4 bf16
// gather); 8 nodes per 256-block. out[d] = (sum w_e h[src_e])/sum w_e.
// ---------------------------------------------------------------------------
__global__ __launch_bounds__(256) void k_agg1(
    const int* __restrict__ rowstart, const int* __restrict__ csr_src,
    const float* __restrict__ asrc, const float* __restrict__ adst,
    const unsigned short* __restrict__ hb, const float* __restrict__ bias,
    const float* __restrict__ g, const float* __restrict__ beta,
    float* __restrict__ out, int N) {
  int d = blockIdx.x * 8 + (threadIdx.x >> 5);
  if (d >= N) return;
  int lane = threadIdx.x & 31;
  int c0 = lane << 2;
  int hd = lane >> 3;
  float ad = adst[d * HEADS + hd];
  int beg = rowstart[d], end = rowstart[d + 1];
  float a0 = 0.f, a1 = 0.f, a2 = 0.f, a3 = 0.f, wsum = 0.f;
  int i = beg;
  for (; i + 2 <= end; i += 2) {
    int sA = csr_src[i], sB = csr_src[i + 1];
    float vA = asrc[sA * HEADS + hd] + ad;
    float vB = asrc[sB * HEADS + hd] + ad;
    ushort4 pA = *(const ushort4*)(hb + (size_t)sA * HID + c0);
    ushort4 pB = *(const ushort4*)(hb + (size_t)sB * HID + c0);
    vA = vA < 0.f ? NEG * vA : vA;
    vB = vB < 0.f ? NEG * vB : vB;
    float wA = __expf(vA), wB = __expf(vB);
    wsum += wA + wB;
    a0 += wA * bf2f(pA.x) + wB * bf2f(pB.x);
    a1 += wA * bf2f(pA.y) + wB * bf2f(pB.y);
    a2 += wA * bf2f(pA.z) + wB * bf2f(pB.z);
    a3 += wA * bf2f(pA.w) + wB * bf2f(pB.w);
  }
  if (i < end) {
    int sA = csr_src[i];
    float vA = asrc[sA * HEADS + hd] + ad;
    ushort4 pA = *(const ushort4*)(hb + (size_t)sA * HID + c0);
    vA = vA < 0.f ? NEG * vA : vA;
    float wA = __expf(vA);
    wsum += wA;
    a0 += wA * bf2f(pA.x);
    a1 += wA * bf2f(pA.y);
    a2 += wA * bf2f(pA.z);
    a3 += wA * bf2f(pA.w);
  }
  float rw = 1.f / wsum;
  float v0 = a0 * rw + bias[c0 + 0];
  float v1 = a1 * rw + bias[c0 + 1];
  float v2 = a2 * rw + bias[c0 + 2];
  float v3 = a3 * rw + bias[c0 + 3];
  v0 = v0 > 0.f ? v0 : (__expf(v0) - 1.f);
  v1 = v1 > 0.f ? v1 : (__expf(v1) - 1.f);
  v2 = v2 > 0.f ? v2 : (__expf(v2) - 1.f);
  v3 = v3 > 0.f ? v3 : (__expf(v3) - 1.f);
  float s1 = v0 + v1 + v2 + v3;
  float s2 = v0 * v0 + v1 * v1 + v2 * v2 + v3 * v3;
#pragma unroll
  for (int o = 16; o > 0; o >>= 1) {
    s1 += __shfl_down(s1, o, 32);
    s2 += __shfl_down(s2, o, 32);
  }
  s1 = __shfl(s1, 0, 32);
  s2 = __shfl(s2, 0, 32);
  float mu = s1 * (1.f / HID);
  float var = s2 * (1.f / HID) - mu * mu;
  float inv = rsqrtf(var + LN_EPS);
  float4 o4;
  o4.x = (v0 - mu) * inv * g[c0 + 0] + beta[c0 + 0];
  o4.y = (v1 - mu) * inv * g[c0 + 1] + beta[c0 + 1];
  o4.z = (v2 - mu) * inv * g[c0 + 2] + beta[c0 + 2];
  o4.w = (v3 - mu) * inv * g[c0 + 3] + beta[c0 + 3];
  *(float4*)(out + (size_t)d * HID + c0) = o4;
}

// ---------------------------------------------------------------------------
// Fused GAT agg + bias + ELU + LN, layer 2 (1 head). Same structure.
// ---------------------------------------------------------------------------
__global__ __launch_bounds__(256) void k_agg2(
    const int* __restrict__ rowstart, const int* __restrict__ csr_src,
    const float* __restrict__ asrc, const float* __restrict__ adst,
    const unsigned short* __restrict__ hb, const float* __restrict__ bias,
    const float* __restrict__ g, const float* __restrict__ beta,
    float* __restrict__ out, int N) {
  int d = blockIdx.x * 8 + (threadIdx.x >> 5);
  if (d >= N) return;
  int lane = threadIdx.x & 31;
  int c0 = lane << 2;
  float ad = adst[d];
  int beg = rowstart[d], end = rowstart[d + 1];
  float a0 = 0.f, a1 = 0.f, a2 = 0.f, a3 = 0.f, wsum = 0.f;
  int i = beg;
  for (; i + 2 <= end; i += 2) {
    int sA = csr_src[i], sB = csr_src[i + 1];
    float vA = asrc[sA] + ad;
    float vB = asrc[sB] + ad;
    ushort4 pA = *(const ushort4*)(hb + (size_t)sA * HID + c0);
    ushort4 pB = *(const ushort4*)(hb + (size_t)sB * HID + c0);
    vA = vA < 0.f ? NEG * vA : vA;
    vB = vB < 0.f ? NEG * vB : vB;
    float wA = __expf(vA), wB = __expf(vB);
    wsum += wA + wB;
    a0 += wA * bf2f(pA.x) + wB * bf2f(pB.x);
    a1 += wA * bf2f(pA.y) + wB * bf2f(pB.y);
    a2 += wA * bf2f(pA.z) + wB * bf2f(pB.z);
    a3 += wA * bf2f(pA.w) + wB * bf2f(pB.w);
  }
  if (i < end) {
    int sA = csr_src[i];
    float vA = asrc[sA] + ad;
    ushort4 pA = *(const ushort4*)(hb + (size_t)sA * HID + c0);
    vA = vA < 0.f ? NEG * vA : vA;
    float wA = __expf(vA);
    wsum += wA;
    a0 += wA * bf2f(pA.x);
    a1 += wA * bf2f(pA.y);
    a2 += wA * bf2f(pA.z);
    a3 += wA * bf2f(pA.w);
  }
  float rw = 1.f / wsum;
  float v0 = a0 * rw + bias[c0 + 0];
  float v1 = a1 * rw + bias[c0 + 1];
  float v2 = a2 * rw + bias[c0 + 2];
  float v3 = a3 * rw + bias[c0 + 3];
  v0 = v0 > 0.f ? v0 : (__expf(v0) - 1.f);
  v1 = v1 > 0.f ? v1 : (__expf(v1) - 1.f);
  v2 = v2 > 0.f ? v2 : (__expf(v2) - 1.f);
  v3 = v3 > 0.f ? v3 : (__expf(v3) - 1.f);
  float s1 = v0 + v1 + v2 + v3;
  float s2 = v0 * v0 + v1 * v1 + v2 * v2 + v3 * v3;
#pragma unroll
  for (int o = 16; o > 0; o >>= 1) {
    s1 += __shfl_down(s1, o, 32);
    s2 += __shfl_down(s2, o, 32);
  }
  s1 = __shfl(s1, 0, 32);
  s2 = __shfl(s2, 0, 32);
  float mu = s1 * (1.f / HID);
  float var = s2 * (1.f / HID) - mu * mu;
  float inv = rsqrtf(var + LN_EPS);
  float4 o4;
  o4.x = (v0 - mu) * inv * g[c0 + 0] + beta[c0 + 0];
  o4.y = (v1 - mu) * inv * g[c0 + 1] + beta[c0 + 1];
  o4.z = (v2 - mu) * inv * g[c0 + 2] + beta[c0 + 2];
  o4.w = (v3 - mu) * inv * g[c0 + 3] + beta[c0 + 3];
  *(float4*)(out + (size_t)d * HID + c0) = o4;
}

// ---------------------------------------------------------------------------
// h2 = x2 @ W2 (N x 128 @ 128 x 128), in-place capable (block-private rows).
// 32 nodes/block; thread = 2 cols x 8 nodes (16 acc); float4 LDS broadcast.
// Writes f32 (for alpha logits) + bf16 copy (for gather).
// ---------------------------------------------------------------------------
__global__ __launch_bounds__(256) void k_gemm2(
    const float* x2, const float* __restrict__ W2, float* h2,
    unsigned short* __restrict__ h2b, int N) {
  __shared__ float xs[32][HID];
  int nb = blockIdx.x * 32;
  float4* dstv = (float4*)(&xs[0][0]);
#pragma unroll
  for (int j = 0; j < 4; ++j) {
    int idx = threadIdx.x + j * 256;          // 1024 float4 = 32 rows
    int row = nb + (idx >> 5);
    float4 z = make_float4(0.f, 0.f, 0.f, 0.f);
    dstv[idx] = (row < N) ? ((const float4*)x2)[(size_t)row * 32 + (idx & 31)] : z;
  }
  __syncthreads();
  int col0 = (threadIdx.x & 63) * 2;
  int ng = threadIdx.x >> 6;                  // 0..3 -> 8 nodes each
  float acc[8][2] = {};
  for (int k = 0; k < HID; k += 4) {
    float2 w0 = *(const float2*)(W2 + (size_t)(k + 0) * HID + col0);
    float2 w1 = *(const float2*)(W2 + (size_t)(k + 1) * HID + col0);
    float2 w2 = *(const float2*)(W2 + (size_t)(k + 2) * HID + col0);
    float2 w3 = *(const float2*)(W2 + (size_t)(k + 3) * HID + col0);
#pragma unroll
    for (int nd = 0; nd < 8; ++nd) {
      float4 xv = *(const float4*)(&xs[ng * 8 + nd][k]);
      acc[nd][0] += xv.x * w0.x + xv.y * w1.x + xv.z * w2.x + xv.w * w3.x;
      acc[nd][1] += xv.x * w0.y + xv.y * w1.y + xv.z * w2.y + xv.w * w3.y;
    }
  }
#pragma unroll
  for (int nd = 0; nd < 8; ++nd) {
    int n = nb + ng * 8 + nd;
    if (n < N) {
      float2 o = make_float2(acc[nd][0], acc[nd][1]);
      *(float2*)(h2 + (size_t)n * HID + col0) = o;
      ushort2 ob;
      ob.x = f2bf(o.x);
      ob.y = f2bf(o.y);
      *(ushort2*)(h2b + (size_t)n * HID + col0) = ob;
    }
  }
}

// ---------------------------------------------------------------------------
// alpha logits layer 2 (heads=1): one wave per node.
// ---------------------------------------------------------------------------
__global__ __launch_bounds__(256) void k_alpha2(
    const float* __restrict__ h2, const float* __restrict__ a_src,
    const float* __restrict__ a_dst, float* __restrict__ asrc,
    float* __restrict__ adst, int N) {
  int n = blockIdx.x * 4 + (threadIdx.x >> 6);
  int l = threadIdx.x & 63;
  if (n >= N) return;
  float v0 = h2[(size_t)n * HID + l];
  float v1 = h2[(size_t)n * HID + 64 + l];
  float av = v0 * a_src[l] + v1 * a_src[64 + l];
  float dv = v0 * a_dst[l] + v1 * a_dst[64 + l];
#pragma unroll
  for (int o = 32; o > 0; o >>= 1) {
    av += __shfl_down(av, o, 64);
    dv += __shfl_down(dv, o, 64);
  }
  if (l == 0) { asrc[n] = av; adst[n] = dv; }
}

extern "C" void kernel_launch(void* const* d_in, const int* in_sizes, int n_in,
                              void* d_out, int out_size, void* d_ws, size_t ws_size,
                              hipStream_t stream) {
  const float* x      = (const float*)d_in[0];
  const int*   ei     = (const int*)d_in[1];
  const float* W1     = (const float*)d_in[2];
  const float* a_src1 = (const float*)d_in[3];
  const float* a_dst1 = (const float*)d_in[4];
  const float* b1     = (const float*)d_in[5];
  const float* g1     = (const float*)d_in[6];
  const float* beta1  = (const float*)d_in[7];
  const float* W2     = (const float*)d_in[8];
  const float* a_src2 = (const float*)d_in[9];
  const float* a_dst2 = (const float*)d_in[10];
  const float* b2     = (const float*)d_in[11];
  const float* g2     = (const float*)d_in[12];
  const float* beta2  = (const float*)d_in[13];
  float* out = (float*)d_out;

  const int N = in_sizes[0] / IN_CH;
  const int E = in_sizes[1] / 2;
  const int Etot = E + N;
  const int nblk = (N + 255) / 256;

  // workspace layout
  float* bufA = (float*)d_ws;                         // x2 -> h2 (in place)
  unsigned short* hb = (unsigned short*)(bufA + (size_t)N * HID);  // bf16 h
  float* asrc1 = (float*)(hb + (size_t)N * HID);
  float* adst1 = asrc1 + (size_t)N * HEADS;
  float* asrc2 = adst1 + (size_t)N * HEADS;
  float* adst2 = asrc2 + N;
  int* deg      = (int*)(adst2 + N);
  int* part     = deg + N;
  int* rowstart = part + N;           // [N+1]
  int* cursor   = rowstart + N + 1;
  int* aux      = cursor + N;         // [<=1024]
  int* csr_src  = aux + 1024;         // [Etot]

  // ---- CSR build (shared by both layers) ----
  hipMemsetAsync(deg, 0, (size_t)N * sizeof(int), stream);
  k_deg<<<(Etot + 255) / 256, 256, 0, stream>>>(ei, E, Etot, deg);
  k_scan1<<<nblk, 256, 0, stream>>>(deg, part, aux, N);
  k_scan2<<<1, 512, 0, stream>>>(aux, nblk);
  k_scan3<<<nblk, 256, 0, stream>>>(part, aux, rowstart, cursor, N, Etot);
  k_scatter<<<(Etot + 255) / 256, 256, 0, stream>>>(ei, E, Etot, cursor, csr_src);

  // ---- Layer 1 ----
  k_gemm1<<<N, 128, 0, stream>>>(x, W1, a_src1, a_dst1, hb, asrc1, adst1, N);
  k_agg1<<<(N + 7) / 8, 256, 0, stream>>>(rowstart, csr_src, asrc1, adst1, hb,
                                          b1, g1, beta1, bufA, N);

  // ---- Layer 2 ----
  k_gemm2<<<(N + 31) / 32, 256, 0, stream>>>(bufA, W2, bufA, hb, N);
  k_alpha2<<<(N + 3) / 4, 256, 0, stream>>>(bufA, a_src2, a_dst2, asrc2, adst2, N);
  k_agg2<<<(N + 7) / 8, 256, 0, stream>>>(rowstart, csr_src, asrc2, adst2, hb,
                                          b2, g2, beta2, out, N);
}